// Round 2
// baseline (5892.529 us; speedup 1.0000x reference)
//
#include <hip/hip_runtime.h>
#include <hip/hip_bf16.h>

typedef __hip_bfloat16 bf16;

#define Bsz 2
#define Tn  1536
#define Cn  1536
#define Hn  8
#define Kn  64
#define Vn  192
// H*K = 512, H*V = 1536, 2T-1 = 3071

__device__ __forceinline__ float toF(float x) { return x; }
__device__ __forceinline__ float toF(bf16 x) { return __bfloat162float(x); }

// ---------------------------------------------------------------------------
// Generic 64x64 tiled GEMM, 4x4 per thread, fp32 accumulate.
// A: [M, Kd], Bw: [Kd, N], C: [M, N]. grid = (N/64, M/64).
// ---------------------------------------------------------------------------
template<typename AT, typename BT, typename OT, bool BIAS>
__global__ __launch_bounds__(256) void gemm64(const AT* __restrict__ A,
                                              const BT* __restrict__ Bw,
                                              const BT* __restrict__ bias,
                                              OT* __restrict__ C,
                                              int Kd, int N, float scale) {
  __shared__ float As[16][68];
  __shared__ float Bs[16][68];
  const int tid = threadIdx.x;
  const int bm = blockIdx.y * 64, bn = blockIdx.x * 64;
  const int tx = tid & 15, ty = tid >> 4;
  float acc[4][4] = {};
  for (int k0 = 0; k0 < Kd; k0 += 16) {
#pragma unroll
    for (int e = 0; e < 4; e++) {
      int idx = tid + e * 256;              // 0..1023
      int m = idx >> 4, ka = idx & 15;      // A tile: 64 rows x 16 k
      As[ka][m] = toF(A[(size_t)(bm + m) * Kd + k0 + ka]);
      int kb = idx >> 6, n = idx & 63;      // B tile: 16 k x 64 n
      Bs[kb][n] = toF(Bw[(size_t)(k0 + kb) * N + bn + n]);
    }
    __syncthreads();
#pragma unroll
    for (int kk = 0; kk < 16; kk++) {
      float a[4], bb[4];
#pragma unroll
      for (int i = 0; i < 4; i++) a[i] = As[kk][ty * 4 + i];
#pragma unroll
      for (int j = 0; j < 4; j++) bb[j] = Bs[kk][tx * 4 + j];
#pragma unroll
      for (int i = 0; i < 4; i++)
#pragma unroll
        for (int j = 0; j < 4; j++) acc[i][j] = fmaf(a[i], bb[j], acc[i][j]);
    }
    __syncthreads();
  }
#pragma unroll
  for (int i = 0; i < 4; i++) {
#pragma unroll
    for (int j = 0; j < 4; j++) {
      float r = acc[i][j] * scale;
      if (BIAS) r += toF(bias[bn + tx * 4 + j]);
      size_t off = (size_t)(bm + ty * 4 + i) * N + bn + tx * 4 + j;
      if constexpr (sizeof(OT) == 2) C[off] = __float2bfloat16(r);
      else                           C[off] = r;
    }
  }
}

// ---------------------------------------------------------------------------
// rk[r, c] = sum_f pe[r, f] * Wr[f, c];  pe is the Borzoi central-mask basis.
// pe[r, i] = (cw[i] > |d|), pe[r, 16+i] = sign(d) * (cw[i] > |d|), d = r-1535.
// cw[i] = 1537^((i+1)/16) - 1 computed in double (margins to the nearest
// integer are >= 0.02, so the comparison can't flip vs the fp32 reference).
// ---------------------------------------------------------------------------
__global__ __launch_bounds__(512) void rk_kernel(const float* __restrict__ Wr,
                                                 float* __restrict__ rk) {
  const int r = blockIdx.x;    // 0..3070
  const int c = threadIdx.x;   // 0..511
  const float d = (float)(r - (Tn - 1));
  const float ad = fabsf(d);
  const float sg = (d > 0.f) ? 1.f : ((d < 0.f) ? -1.f : 0.f);
  float acc = 0.f;
#pragma unroll
  for (int i = 0; i < 16; i++) {
    double cw = exp(log((double)(Tn + 1)) * (double)(i + 1) / 16.0) - 1.0;
    if ((float)cw > ad) {
      acc += Wr[i * 512 + c] + sg * Wr[(16 + i) * 512 + c];
    }
  }
  rk[(size_t)r * 512 + c] = acc;
}

// ---------------------------------------------------------------------------
// Fused flash-style attention with relative positional bias.
// logits[t,s] = (q[t]+rwb) . k[s]  +  (q[t]+rrb) . rk[s - t + 1535]
// (relative_shift reduces to this gather; verified against the pad/reshape
//  trick by hand at T=2.)
// One block = (b, h, 32-query tile); 4 waves x 8 rows each; s-chunks of 64.
// q pre-scaled by K^-0.5.  att layout: [B*T, H*V].
// ---------------------------------------------------------------------------
__global__ __launch_bounds__(256) void attn_kernel(
    const float* __restrict__ q, const float* __restrict__ kmat,
    const float* __restrict__ vmat, const float* __restrict__ rkm,
    const float* __restrict__ rwb, const float* __restrict__ rrb,
    float* __restrict__ att) {
  __shared__ float qw[32][68];
  __shared__ float qr[32][68];
  __shared__ float kt[64][68];
  __shared__ bf16  vt[64][192];   // bf16 to fit 64KB static LDS

  const int t0 = blockIdx.x * 32;
  const int h  = blockIdx.y;
  const int b  = blockIdx.z;
  const int tid = threadIdx.x;
  const int lane = tid & 63;
  const int w = tid >> 6;

  // stage q tiles (+ per-head biases)
#pragma unroll
  for (int e = 0; e < 8; e++) {            // 32*64 / 256
    int idx = tid + e * 256;
    int i = idx >> 6, j = idx & 63;
    float qv = q[(size_t)(b * Tn + t0 + i) * 512 + h * 64 + j];
    qw[i][j] = qv + rwb[h * 64 + j];
    qr[i][j] = qv + rrb[h * 64 + j];
  }

  float m_i[8], l_i[8], acc[8][3];
#pragma unroll
  for (int r = 0; r < 8; r++) {
    m_i[r] = -1e30f; l_i[r] = 0.f;
    acc[r][0] = acc[r][1] = acc[r][2] = 0.f;
  }

  for (int s0 = 0; s0 < Tn; s0 += 64) {
    __syncthreads();                       // protect kt/vt (and qw on iter 0)
#pragma unroll
    for (int e = 0; e < 16; e++) {         // 64*64 / 256
      int idx = tid + e * 256;
      int s = idx >> 6, j = idx & 63;
      kt[s][j] = kmat[(size_t)(b * Tn + s0 + s) * 512 + h * 64 + j];
    }
#pragma unroll
    for (int e = 0; e < 48; e++) {         // 64*192 / 256
      int idx = tid + e * 256;
      int s = idx / 192, vv = idx % 192;
      vt[s][vv] = __float2bfloat16(
          vmat[(size_t)(b * Tn + s0 + s) * 1536 + h * 192 + vv]);
    }
    __syncthreads();

#pragma unroll 1
    for (int r = 0; r < 8; r++) {
      const int ti = w * 8 + r;
      const int tg = t0 + ti;
      const int d = s0 + lane - tg + (Tn - 1);      // in [0, 3070]
      const float* rkrow = rkm + (size_t)d * 512 + h * 64;
      float lg = 0.f;
#pragma unroll
      for (int j = 0; j < 64; j += 4) {
        float4 kv  = *(const float4*)&kt[lane][j];
        float4 qwv = *(const float4*)&qw[ti][j];
        float4 qrv = *(const float4*)&qr[ti][j];
        float4 rv  = *(const float4*)&rkrow[j];
        lg += qwv.x * kv.x + qwv.y * kv.y + qwv.z * kv.z + qwv.w * kv.w;
        lg += qrv.x * rv.x + qrv.y * rv.y + qrv.z * rv.z + qrv.w * rv.w;
      }
      // online softmax (wave = 64 lanes, one key per lane)
      float mx = lg;
#pragma unroll
      for (int off = 32; off >= 1; off >>= 1) mx = fmaxf(mx, __shfl_xor(mx, off));
      float mnew  = fmaxf(m_i[r], mx);
      float alpha = __expf(m_i[r] - mnew);
      float p     = __expf(lg - mnew);
      float rs = p;
#pragma unroll
      for (int off = 32; off >= 1; off >>= 1) rs += __shfl_xor(rs, off);
      m_i[r] = mnew;
      l_i[r] = l_i[r] * alpha + rs;
      acc[r][0] *= alpha; acc[r][1] *= alpha; acc[r][2] *= alpha;
#pragma unroll 4
      for (int s = 0; s < 64; s++) {
        float ps = __shfl(p, s);
        acc[r][0] = fmaf(ps, __bfloat162float(vt[s][lane]),       acc[r][0]);
        acc[r][1] = fmaf(ps, __bfloat162float(vt[s][lane + 64]),  acc[r][1]);
        acc[r][2] = fmaf(ps, __bfloat162float(vt[s][lane + 128]), acc[r][2]);
      }
    }
  }

#pragma unroll
  for (int r = 0; r < 8; r++) {
    const int tg = t0 + w * 8 + r;
    float inv = 1.f / l_i[r];
    size_t base = (size_t)(b * Tn + tg) * 1536 + h * 192;
    att[base + lane]       = acc[r][0] * inv;
    att[base + lane + 64]  = acc[r][1] * inv;
    att[base + lane + 128] = acc[r][2] * inv;
  }
}

// ---------------------------------------------------------------------------
extern "C" void kernel_launch(void* const* d_in, const int* in_sizes, int n_in,
                              void* d_out, int out_size, void* d_ws, size_t ws_size,
                              hipStream_t stream) {
  // Reference dtypes are all float32 (setup_inputs uses jnp.float32).
  const float* x   = (const float*)d_in[0];
  const float* Wq  = (const float*)d_in[1];
  const float* Wk  = (const float*)d_in[2];
  const float* Wv  = (const float*)d_in[3];
  const float* Wr  = (const float*)d_in[4];
  const float* rwb = (const float*)d_in[5];
  const float* rrb = (const float*)d_in[6];
  const float* Wo  = (const float*)d_in[7];
  const float* bo  = (const float*)d_in[8];
  float* out = (float*)d_out;

  const int M = Bsz * Tn;                 // 3072
  float* qf  = (float*)d_ws;              // [3072, 512] pre-scaled by K^-0.5
  float* kf  = qf + (size_t)M * 512;      // [3072, 512]
  float* vf  = kf + (size_t)M * 512;      // [3072, 1536]
  float* rkf = vf + (size_t)M * 1536;     // [3071, 512]
  float* att = rkf + (size_t)3071 * 512;  // [3072, 1536]

  dim3 blk(256);
  gemm64<float, float, float, false><<<dim3(512 / 64, M / 64), blk, 0, stream>>>(
      x, Wq, nullptr, qf, Cn, 512, 0.125f);           // K^-0.5 = 1/8
  gemm64<float, float, float, false><<<dim3(512 / 64, M / 64), blk, 0, stream>>>(
      x, Wk, nullptr, kf, Cn, 512, 1.0f);
  gemm64<float, float, float, false><<<dim3(1536 / 64, M / 64), blk, 0, stream>>>(
      x, Wv, nullptr, vf, Cn, 1536, 1.0f);
  rk_kernel<<<dim3(2 * Tn - 1), dim3(512), 0, stream>>>(Wr, rkf);
  attn_kernel<<<dim3(Tn / 32, Hn, Bsz), blk, 0, stream>>>(
      qf, kf, vf, rkf, rwb, rrb, att);
  gemm64<float, float, float, true><<<dim3(1536 / 64, M / 64), blk, 0, stream>>>(
      att, Wo, bo, out, 1536, 1536, 1.0f);
}

// Round 3
// 921.222 us; speedup vs baseline: 6.3964x; 6.3964x over previous
//
#include <hip/hip_runtime.h>
#include <hip/hip_bf16.h>

typedef __hip_bfloat16 bf16;
typedef unsigned short ushort;
typedef __attribute__((ext_vector_type(8))) short short8;
typedef __attribute__((ext_vector_type(4))) float f32x4;

#define Bsz 2
#define Tn  1536
#define Cn  1536
#define Hn  8
#define Kn  64
#define Vn  192
// H*K = 512, H*V = 1536, 2T-1 = 3071

__device__ __forceinline__ ushort f2bs(float f) {
  union { bf16 h; ushort u; } cv;
  cv.h = __float2bfloat16(f);
  return cv.u;
}

// ---------------------------------------------------------------------------
// 64x64 tiled fp32 GEMM, 4x4/thread. OUTMODE: 0=f32, 1=bf16, 2=bf16 C^T.
// A:[M,Kd] f32, Bw:[Kd,N] f32. Mode 2 writes C^T [N][Mtot] (Mtot = M).
// ---------------------------------------------------------------------------
template<int OUTMODE, bool BIAS>
__global__ __launch_bounds__(256) void gemm64(const float* __restrict__ A,
                                              const float* __restrict__ Bw,
                                              const float* __restrict__ bias,
                                              void* __restrict__ Cout,
                                              int Kd, int N, int Mtot,
                                              float scale) {
  __shared__ float As[16][68];
  __shared__ float Bs[16][68];
  const int tid = threadIdx.x;
  const int bm = blockIdx.y * 64, bn = blockIdx.x * 64;
  const int tx = tid & 15, ty = tid >> 4;
  float acc[4][4] = {};
  for (int k0 = 0; k0 < Kd; k0 += 16) {
#pragma unroll
    for (int e = 0; e < 4; e++) {
      int idx = tid + e * 256;
      int m = idx >> 4, ka = idx & 15;
      As[ka][m] = A[(size_t)(bm + m) * Kd + k0 + ka];
      int kb = idx >> 6, n = idx & 63;
      Bs[kb][n] = Bw[(size_t)(k0 + kb) * N + bn + n];
    }
    __syncthreads();
#pragma unroll
    for (int kk = 0; kk < 16; kk++) {
      float a[4], bb[4];
#pragma unroll
      for (int i = 0; i < 4; i++) a[i] = As[kk][ty * 4 + i];
#pragma unroll
      for (int j = 0; j < 4; j++) bb[j] = Bs[kk][tx * 4 + j];
#pragma unroll
      for (int i = 0; i < 4; i++)
#pragma unroll
        for (int j = 0; j < 4; j++) acc[i][j] = fmaf(a[i], bb[j], acc[i][j]);
    }
    __syncthreads();
  }
  if (OUTMODE == 2) {
    ushort* C = (ushort*)Cout;
#pragma unroll
    for (int j = 0; j < 4; j++) {
      unsigned lo = (unsigned)f2bs(acc[0][j] * scale) |
                    ((unsigned)f2bs(acc[1][j] * scale) << 16);
      unsigned hi = (unsigned)f2bs(acc[2][j] * scale) |
                    ((unsigned)f2bs(acc[3][j] * scale) << 16);
      uint2 val; val.x = lo; val.y = hi;
      *(uint2*)(C + (size_t)(bn + tx * 4 + j) * Mtot + bm + ty * 4) = val;
    }
  } else {
#pragma unroll
    for (int i = 0; i < 4; i++) {
#pragma unroll
      for (int j = 0; j < 4; j++) {
        float r = acc[i][j] * scale;
        if (BIAS) r += bias[bn + tx * 4 + j];
        size_t off = (size_t)(bm + ty * 4 + i) * N + bn + tx * 4 + j;
        if (OUTMODE == 1) ((ushort*)Cout)[off] = f2bs(r);
        else              ((float*)Cout)[off] = r;
      }
    }
  }
}

// ---------------------------------------------------------------------------
// rk[r,c] (bf16) from the Borzoi central-mask basis (double-precision widths;
// margins to integers >= 0.02, so no comparison can flip vs fp32 reference).
// ---------------------------------------------------------------------------
__global__ __launch_bounds__(512) void rk_kernel(const float* __restrict__ Wr,
                                                 ushort* __restrict__ rk) {
  const int r = blockIdx.x;
  const int c = threadIdx.x;
  const float d = (float)(r - (Tn - 1));
  const float ad = fabsf(d);
  const float sg = (d > 0.f) ? 1.f : ((d < 0.f) ? -1.f : 0.f);
  float acc = 0.f;
#pragma unroll
  for (int i = 0; i < 16; i++) {
    double cw = exp(log((double)(Tn + 1)) * (double)(i + 1) / 16.0) - 1.0;
    if ((float)cw > ad) acc += Wr[i * 512 + c] + sg * Wr[(16 + i) * 512 + c];
  }
  rk[(size_t)r * 512 + c] = f2bs(acc);
}

// ---------------------------------------------------------------------------
// MFMA flash attention with relative positional bias.
// Block = (b, h, 32-query tile); 2 waves x 16 rows; s-chunks of 64.
// logits[t,s] = (q[t]+rwb).k[s] + P_rel[t, (s-s0)-(t-t0)+31],
//   P_rel[t,j] = (q[t]+rrb).rk[Dbase+j],  Dbase = s0-t0+1504.
// LDS: X region = K[64][72] + rkl[96][72]  (overlaid by Vt[192][72] in PV
// phase); prl[32][100] f32 (per-wave rel logits, same-wave RAW only);
// Pp[32][72] bf16 (probs, C-layout -> A-layout round trip).
// ---------------------------------------------------------------------------
__global__ __launch_bounds__(128) void attn_mfma(
    const float* __restrict__ qf, const ushort* __restrict__ kb,
    const ushort* __restrict__ vtb, const ushort* __restrict__ rkb,
    const float* __restrict__ rwb, const float* __restrict__ rrb,
    float* __restrict__ att) {
  __shared__ __align__(16) char smem[45056];
  ushort* Klds = (ushort*)smem;                    // [64][72]
  ushort* RKl  = (ushort*)(smem + 9216);           // [96][72]
  ushort* Vt   = (ushort*)smem;                    // [192][72] overlays K+RK
  float*  prl  = (float*)(smem + 27648);           // [32][100]
  ushort* Pp   = (ushort*)(smem + 40448);          // [32][72]

  const int t0 = blockIdx.x * 32;
  const int h  = blockIdx.y;
  const int b  = blockIdx.z;
  const int bT = b * Tn;
  const int tid = threadIdx.x;
  const int w = tid >> 6;
  const int lane = tid & 63;
  const int quad = lane >> 4;
  const int ln = lane & 15;

  // Q fragments (A-operand layout: m=ln, k=quad*8+e+32*ks), +w/+r biases.
  short8 qw8[2], qr8[2];
  {
    const float* qrow = qf + (size_t)(bT + t0 + 16 * w + ln) * 512 + h * 64;
#pragma unroll
    for (int ks = 0; ks < 2; ks++) {
      int k0 = quad * 8 + ks * 32;
#pragma unroll
      for (int e = 0; e < 8; e++) {
        float qv = qrow[k0 + e];
        qw8[ks][e] = (short)f2bs(qv + rwb[h * 64 + k0 + e]);
        qr8[ks][e] = (short)f2bs(qv + rrb[h * 64 + k0 + e]);
      }
    }
  }

  f32x4 Oacc[12];
  float m_i[4], l_i[4];
#pragma unroll
  for (int vt = 0; vt < 12; vt++) Oacc[vt] = (f32x4){0.f, 0.f, 0.f, 0.f};
#pragma unroll
  for (int r = 0; r < 4; r++) { m_i[r] = -1e30f; l_i[r] = 0.f; }

  for (int s0 = 0; s0 < Tn; s0 += 64) {
    const int Dbase = s0 - t0 + 1504;
    __syncthreads();  // prev PV done reading Vt
    // stage K [64][72]
#pragma unroll
    for (int e = 0; e < 8; e++) {
      int idx = tid + e * 128;
      int s = idx >> 4, kq = idx & 15;
      *(uint2*)(Klds + s * 72 + kq * 4) =
          *(const uint2*)(kb + (size_t)(bT + s0 + s) * 512 + h * 64 + kq * 4);
    }
    // stage rkl [96][72] (row 95 clamped; only j<95 is ever gathered)
#pragma unroll
    for (int e = 0; e < 12; e++) {
      int idx = tid + e * 128;
      int j = idx >> 4, kq = idx & 15;
      int jr = Dbase + j; jr = jr > 3070 ? 3070 : jr;
      *(uint2*)(RKl + j * 72 + kq * 4) =
          *(const uint2*)(rkb + (size_t)jr * 512 + h * 64 + kq * 4);
    }
    __syncthreads();

    // ---- S phase: content + rel MFMAs ----
    f32x4 Sacc[4], Pacc[6];
#pragma unroll
    for (int ct = 0; ct < 4; ct++) {
      Sacc[ct] = (f32x4){0.f, 0.f, 0.f, 0.f};
#pragma unroll
      for (int ks = 0; ks < 2; ks++) {
        short8 bfr = *(const short8*)(Klds + (16 * ct + ln) * 72 + quad * 8 + ks * 32);
        Sacc[ct] = __builtin_amdgcn_mfma_f32_16x16x32_bf16(qw8[ks], bfr, Sacc[ct], 0, 0, 0);
      }
    }
#pragma unroll
    for (int jt = 0; jt < 6; jt++) {
      Pacc[jt] = (f32x4){0.f, 0.f, 0.f, 0.f};
#pragma unroll
      for (int ks = 0; ks < 2; ks++) {
        short8 bfr = *(const short8*)(RKl + (16 * jt + ln) * 72 + quad * 8 + ks * 32);
        Pacc[jt] = __builtin_amdgcn_mfma_f32_16x16x32_bf16(qr8[ks], bfr, Pacc[jt], 0, 0, 0);
      }
    }
    // write rel logits (C-layout) to prl, own-wave rows only
#pragma unroll
    for (int jt = 0; jt < 6; jt++)
#pragma unroll
      for (int r = 0; r < 4; r++)
        prl[(16 * w + 4 * quad + r) * 100 + 16 * jt + ln] = Pacc[jt][r];
    __asm__ volatile("s_waitcnt lgkmcnt(0)" ::: "memory");

    // gather rel into S, online softmax
    float pS[4][4];
#pragma unroll
    for (int ct = 0; ct < 4; ct++)
#pragma unroll
      for (int r = 0; r < 4; r++) {
        int row = 4 * quad + r;
        int j = 16 * ct + ln - 16 * w - row + 31;
        pS[ct][r] = Sacc[ct][r] + prl[(16 * w + row) * 100 + j];
      }
    float alpha[4];
#pragma unroll
    for (int r = 0; r < 4; r++) {
      float mx = fmaxf(fmaxf(pS[0][r], pS[1][r]), fmaxf(pS[2][r], pS[3][r]));
#pragma unroll
      for (int off = 8; off >= 1; off >>= 1) mx = fmaxf(mx, __shfl_xor(mx, off));
      float mnew = fmaxf(m_i[r], mx);
      alpha[r] = __expf(m_i[r] - mnew);
      m_i[r] = mnew;
      float rs = 0.f;
#pragma unroll
      for (int ct = 0; ct < 4; ct++) {
        pS[ct][r] = __expf(pS[ct][r] - mnew);
        rs += pS[ct][r];
      }
#pragma unroll
      for (int off = 8; off >= 1; off >>= 1) rs += __shfl_xor(rs, off);
      l_i[r] = l_i[r] * alpha[r] + rs;
    }
#pragma unroll
    for (int vt = 0; vt < 12; vt++)
#pragma unroll
      for (int r = 0; r < 4; r++) Oacc[vt][r] *= alpha[r];
    // probs -> Pp (bf16), C-layout rows; re-read below in A-layout (same wave)
#pragma unroll
    for (int ct = 0; ct < 4; ct++)
#pragma unroll
      for (int r = 0; r < 4; r++)
        Pp[(16 * w + 4 * quad + r) * 72 + 16 * ct + ln] = f2bs(pS[ct][r]);
    __asm__ volatile("s_waitcnt lgkmcnt(0)" ::: "memory");

    __syncthreads();  // all waves done reading K/rkl
    // stage Vt [192][72] (overlays K+rkl)
#pragma unroll
    for (int e = 0; e < 24; e++) {
      int idx = tid + e * 128;
      int v = idx >> 4, sq = idx & 15;
      *(uint2*)(Vt + v * 72 + sq * 4) =
          *(const uint2*)(vtb + (size_t)(h * 192 + v) * 3072 + bT + s0 + sq * 4);
    }
    __syncthreads();

    // ---- PV phase ----
    short8 afr[2];
#pragma unroll
    for (int ks = 0; ks < 2; ks++)
      afr[ks] = *(const short8*)(Pp + (16 * w + ln) * 72 + quad * 8 + ks * 32);
#pragma unroll
    for (int vt = 0; vt < 12; vt++) {
#pragma unroll
      for (int ks = 0; ks < 2; ks++) {
        short8 bfr = *(const short8*)(Vt + (16 * vt + ln) * 72 + quad * 8 + ks * 32);
        Oacc[vt] = __builtin_amdgcn_mfma_f32_16x16x32_bf16(afr[ks], bfr, Oacc[vt], 0, 0, 0);
      }
    }
  }

  // epilogue
  float inv[4];
#pragma unroll
  for (int r = 0; r < 4; r++) inv[r] = 1.f / l_i[r];
#pragma unroll
  for (int vt = 0; vt < 12; vt++)
#pragma unroll
    for (int r = 0; r < 4; r++) {
      int t = t0 + 16 * w + 4 * quad + r;
      att[(size_t)(bT + t) * 1536 + h * 192 + 16 * vt + ln] = Oacc[vt][r] * inv[r];
    }
}

// ---------------------------------------------------------------------------
extern "C" void kernel_launch(void* const* d_in, const int* in_sizes, int n_in,
                              void* d_out, int out_size, void* d_ws, size_t ws_size,
                              hipStream_t stream) {
  const float* x   = (const float*)d_in[0];
  const float* Wq  = (const float*)d_in[1];
  const float* Wk  = (const float*)d_in[2];
  const float* Wv  = (const float*)d_in[3];
  const float* Wr  = (const float*)d_in[4];
  const float* rwb = (const float*)d_in[5];
  const float* rrb = (const float*)d_in[6];
  const float* Wo  = (const float*)d_in[7];
  const float* bo  = (const float*)d_in[8];
  float* out = (float*)d_out;

  const int M = Bsz * Tn;  // 3072
  char* ws = (char*)d_ws;
  float*  qf  = (float*)ws;                      // [3072,512] f32 (pre-scaled)
  ushort* kb  = (ushort*)(ws + 6291456);         // [3072,512] bf16
  ushort* vtb = (ushort*)(ws + 9437184);         // [1536,3072] bf16 (V^T)
  ushort* rkb = (ushort*)(ws + 18874368);        // [3071,512] bf16
  float*  att = (float*)(ws + 22020096);         // [3072,1536] f32

  dim3 blk(256);
  gemm64<0, false><<<dim3(8, 48), blk, 0, stream>>>(x, Wq, nullptr, qf, Cn, 512, M, 0.125f);
  gemm64<1, false><<<dim3(8, 48), blk, 0, stream>>>(x, Wk, nullptr, kb, Cn, 512, M, 1.0f);
  gemm64<2, false><<<dim3(24, 48), blk, 0, stream>>>(x, Wv, nullptr, vtb, Cn, 1536, M, 1.0f);
  rk_kernel<<<dim3(2 * Tn - 1), dim3(512), 0, stream>>>(Wr, rkb);
  attn_mfma<<<dim3(Tn / 32, Hn, Bsz), dim3(128), 0, stream>>>(
      qf, kb, vtb, rkb, rwb, rrb, att);
  gemm64<0, true><<<dim3(24, 48), blk, 0, stream>>>(att, Wo, bo, out, 1536, 1536, M, 1.0f);
}

// Round 4
// 351.586 us; speedup vs baseline: 16.7598x; 2.6202x over previous
//
#include <hip/hip_runtime.h>
#include <hip/hip_bf16.h>

typedef __hip_bfloat16 bf16;
typedef unsigned short ushort;
typedef unsigned int uint;
typedef __attribute__((ext_vector_type(8))) short short8;
typedef __attribute__((ext_vector_type(4))) float f32x4;

#define Bsz 2
#define Tn  1536
#define Cn  1536
#define Hn  8
#define Kn  64
#define Vn  192
// H*K = 512, H*V = 1536, 2T-1 = 3071

__device__ __forceinline__ ushort f2bs(float f) {
  union { bf16 h; ushort u; } cv;
  cv.h = __float2bfloat16(f);
  return cv.u;
}
__device__ __forceinline__ float bs2f(ushort u) {
  union { float f; uint v; } cv; cv.v = ((uint)u) << 16; return cv.f;
}

// async global->LDS, 16B per lane; LDS dest must be wave-uniform base + lane*16
__device__ __forceinline__ void gld_lds16(const ushort* g, ushort* l) {
  __builtin_amdgcn_global_load_lds(
      (const __attribute__((address_space(1))) uint*)g,
      (__attribute__((address_space(3))) uint*)l, 16, 0, 0);
}

// ---------------------------------------------------------------------------
// f32 -> bf16 elementwise (x), vectorized x4
// ---------------------------------------------------------------------------
__global__ __launch_bounds__(256) void cvt_bf16(const float* __restrict__ in,
                                                ushort* __restrict__ out, int n4) {
  int i = blockIdx.x * 256 + threadIdx.x;
  if (i < n4) {
    float4 v = ((const float4*)in)[i];
    uint2 o;
    o.x = (uint)f2bs(v.x) | ((uint)f2bs(v.y) << 16);
    o.y = (uint)f2bs(v.z) | ((uint)f2bs(v.w) << 16);
    ((uint2*)out)[i] = o;
  }
}

// ---------------------------------------------------------------------------
// transpose + convert: in f32 [R][Cc] -> out bf16 [Cc][R]. 32x32 LDS tiles.
// ---------------------------------------------------------------------------
__global__ __launch_bounds__(256) void transp_bf16(const float* __restrict__ in,
                                                   ushort* __restrict__ out,
                                                   int R, int Cc) {
  __shared__ float tile[32][33];
  const int bx = blockIdx.x * 32;   // col base (becomes out row)
  const int by = blockIdx.y * 32;   // row base
  const int tx = threadIdx.x & 31, ty = threadIdx.x >> 5;
#pragma unroll
  for (int i = 0; i < 32; i += 8)
    tile[ty + i][tx] = in[(size_t)(by + ty + i) * Cc + bx + tx];
  __syncthreads();
#pragma unroll
  for (int i = 0; i < 32; i += 8)
    out[(size_t)(bx + ty + i) * R + by + tx] = f2bs(tile[tx][ty + i]);
}

// ---------------------------------------------------------------------------
// rk[r,c] (bf16) from the Borzoi central-mask basis (double widths; margins
// to integers >= 0.02 so no comparison flips vs the fp32 reference).
// ---------------------------------------------------------------------------
__global__ __launch_bounds__(512) void rk_kernel(const float* __restrict__ Wr,
                                                 ushort* __restrict__ rk) {
  const int r = blockIdx.x;
  const int c = threadIdx.x;
  const float d = (float)(r - (Tn - 1));
  const float ad = fabsf(d);
  const float sg = (d > 0.f) ? 1.f : ((d < 0.f) ? -1.f : 0.f);
  float acc = 0.f;
#pragma unroll
  for (int i = 0; i < 16; i++) {
    double cw = exp(log((double)(Tn + 1)) * (double)(i + 1) / 16.0) - 1.0;
    if ((float)cw > ad) acc += Wr[i * 512 + c] + sg * Wr[(16 + i) * 512 + c];
  }
  rk[(size_t)r * 512 + c] = f2bs(acc);
}

// ---------------------------------------------------------------------------
// Fused QKV MFMA GEMM: xb [3072][1536] bf16 @ Wt^T-layout [2560][1536] bf16.
// 128x128 block tile, BK=32, 4 waves each 64x64 (4x4 of 16x16x32 MFMA).
// Epilogue by n-range: [0,512) q bf16*0.125 -> qb [3072][512]
//                      [512,1024) k bf16    -> kb [3072][512]
//                      [1024,2560) v bf16   -> vtb [1536][3072] (transposed)
// ---------------------------------------------------------------------------
__global__ __launch_bounds__(256) void gemm_qkv(
    const ushort* __restrict__ xb, const ushort* __restrict__ Wt,
    ushort* __restrict__ qb, ushort* __restrict__ kb, ushort* __restrict__ vtb) {
  __shared__ ushort Al[128 * 32];
  __shared__ ushort Bl[128 * 32];
  const int tid = threadIdx.x;
  const int w = tid >> 6, lane = tid & 63, quad = lane >> 4, ln = lane & 15;
  const int bm = blockIdx.y * 128, bn = blockIdx.x * 128;
  const int wm = (w & 1) * 64, wn = (w >> 1) * 64;
  f32x4 acc[4][4];
#pragma unroll
  for (int i = 0; i < 4; i++)
#pragma unroll
    for (int j = 0; j < 4; j++) acc[i][j] = (f32x4){0.f, 0.f, 0.f, 0.f};

  for (int k0 = 0; k0 < 1536; k0 += 32) {
    __syncthreads();
#pragma unroll
    for (int st = 0; st < 2; st++) {
      int idx = tid + st * 256;               // 0..511
      int row = idx >> 2, col = (idx & 3) * 8;
      gld_lds16(xb + (size_t)(bm + row) * 1536 + k0 + col, Al + idx * 8);
      gld_lds16(Wt + (size_t)(bn + row) * 1536 + k0 + col, Bl + idx * 8);
    }
    __syncthreads();
    short8 af[4], bfr[4];
#pragma unroll
    for (int t = 0; t < 4; t++) {
      af[t]  = *(const short8*)(Al + (wm + t * 16 + ln) * 32 + quad * 8);
      bfr[t] = *(const short8*)(Bl + (wn + t * 16 + ln) * 32 + quad * 8);
    }
#pragma unroll
    for (int mt = 0; mt < 4; mt++)
#pragma unroll
      for (int nt = 0; nt < 4; nt++)
        acc[mt][nt] = __builtin_amdgcn_mfma_f32_16x16x32_bf16(
            af[mt], bfr[nt], acc[mt][nt], 0, 0, 0);
  }

  if (bn < 512) {               // q, pre-scaled by K^-0.5
#pragma unroll
    for (int mt = 0; mt < 4; mt++)
#pragma unroll
      for (int nt = 0; nt < 4; nt++)
#pragma unroll
        for (int r = 0; r < 4; r++) {
          int m = bm + wm + mt * 16 + quad * 4 + r;
          int n = bn + wn + nt * 16 + ln;
          qb[(size_t)m * 512 + n] = f2bs(acc[mt][nt][r] * 0.125f);
        }
  } else if (bn < 1024) {       // k
#pragma unroll
    for (int mt = 0; mt < 4; mt++)
#pragma unroll
      for (int nt = 0; nt < 4; nt++)
#pragma unroll
        for (int r = 0; r < 4; r++) {
          int m = bm + wm + mt * 16 + quad * 4 + r;
          int n = bn - 512 + wn + nt * 16 + ln;
          kb[(size_t)m * 512 + n] = f2bs(acc[mt][nt][r]);
        }
  } else {                      // v, transposed store [vcol][m]
#pragma unroll
    for (int mt = 0; mt < 4; mt++)
#pragma unroll
      for (int nt = 0; nt < 4; nt++) {
        int vcol = bn - 1024 + wn + nt * 16 + ln;
        int m0 = bm + wm + mt * 16 + quad * 4;
        uint2 val;
        val.x = (uint)f2bs(acc[mt][nt][0]) | ((uint)f2bs(acc[mt][nt][1]) << 16);
        val.y = (uint)f2bs(acc[mt][nt][2]) | ((uint)f2bs(acc[mt][nt][3]) << 16);
        *(uint2*)(vtb + (size_t)vcol * 3072 + m0) = val;
      }
  }
}

// ---------------------------------------------------------------------------
// Output MFMA GEMM: att [3072][1536] bf16 @ Wot [1536][1536] bf16 (^T layout)
// + bo, f32 out.
// ---------------------------------------------------------------------------
__global__ __launch_bounds__(256) void gemm_out(
    const ushort* __restrict__ att, const ushort* __restrict__ Wot,
    const float* __restrict__ bo, float* __restrict__ out) {
  __shared__ ushort Al[128 * 32];
  __shared__ ushort Bl[128 * 32];
  const int tid = threadIdx.x;
  const int w = tid >> 6, lane = tid & 63, quad = lane >> 4, ln = lane & 15;
  const int bm = blockIdx.y * 128, bn = blockIdx.x * 128;
  const int wm = (w & 1) * 64, wn = (w >> 1) * 64;
  f32x4 acc[4][4];
#pragma unroll
  for (int i = 0; i < 4; i++)
#pragma unroll
    for (int j = 0; j < 4; j++) acc[i][j] = (f32x4){0.f, 0.f, 0.f, 0.f};

  for (int k0 = 0; k0 < 1536; k0 += 32) {
    __syncthreads();
#pragma unroll
    for (int st = 0; st < 2; st++) {
      int idx = tid + st * 256;
      int row = idx >> 2, col = (idx & 3) * 8;
      gld_lds16(att + (size_t)(bm + row) * 1536 + k0 + col, Al + idx * 8);
      gld_lds16(Wot + (size_t)(bn + row) * 1536 + k0 + col, Bl + idx * 8);
    }
    __syncthreads();
    short8 af[4], bfr[4];
#pragma unroll
    for (int t = 0; t < 4; t++) {
      af[t]  = *(const short8*)(Al + (wm + t * 16 + ln) * 32 + quad * 8);
      bfr[t] = *(const short8*)(Bl + (wn + t * 16 + ln) * 32 + quad * 8);
    }
#pragma unroll
    for (int mt = 0; mt < 4; mt++)
#pragma unroll
      for (int nt = 0; nt < 4; nt++)
        acc[mt][nt] = __builtin_amdgcn_mfma_f32_16x16x32_bf16(
            af[mt], bfr[nt], acc[mt][nt], 0, 0, 0);
  }
#pragma unroll
  for (int mt = 0; mt < 4; mt++)
#pragma unroll
    for (int nt = 0; nt < 4; nt++)
#pragma unroll
      for (int r = 0; r < 4; r++) {
        int m = bm + wm + mt * 16 + quad * 4 + r;
        int n = bn + wn + nt * 16 + ln;
        out[(size_t)m * 1536 + n] = acc[mt][nt][r] + bo[n];
      }
}

// ---------------------------------------------------------------------------
// MFMA flash attention with relative positional bias (unchanged structure;
// q now bf16 in, att now bf16 out).
// ---------------------------------------------------------------------------
__global__ __launch_bounds__(128) void attn_mfma(
    const ushort* __restrict__ qb, const ushort* __restrict__ kb,
    const ushort* __restrict__ vtb, const ushort* __restrict__ rkb,
    const float* __restrict__ rwb, const float* __restrict__ rrb,
    ushort* __restrict__ att) {
  __shared__ __align__(16) char smem[45056];
  ushort* Klds = (ushort*)smem;                    // [64][72]
  ushort* RKl  = (ushort*)(smem + 9216);           // [96][72]
  ushort* Vt   = (ushort*)smem;                    // [192][72] overlays K+RK
  float*  prl  = (float*)(smem + 27648);           // [32][100]
  ushort* Pp   = (ushort*)(smem + 40448);          // [32][72]

  const int t0 = blockIdx.x * 32;
  const int h  = blockIdx.y;
  const int b  = blockIdx.z;
  const int bT = b * Tn;
  const int tid = threadIdx.x;
  const int w = tid >> 6;
  const int lane = tid & 63;
  const int quad = lane >> 4;
  const int ln = lane & 15;

  short8 qw8[2], qr8[2];
  {
    const ushort* qrow = qb + (size_t)(bT + t0 + 16 * w + ln) * 512 + h * 64;
#pragma unroll
    for (int ks = 0; ks < 2; ks++) {
      int k0 = quad * 8 + ks * 32;
#pragma unroll
      for (int e = 0; e < 8; e++) {
        float qv = bs2f(qrow[k0 + e]);
        qw8[ks][e] = (short)f2bs(qv + rwb[h * 64 + k0 + e]);
        qr8[ks][e] = (short)f2bs(qv + rrb[h * 64 + k0 + e]);
      }
    }
  }

  f32x4 Oacc[12];
  float m_i[4], l_i[4];
#pragma unroll
  for (int vt = 0; vt < 12; vt++) Oacc[vt] = (f32x4){0.f, 0.f, 0.f, 0.f};
#pragma unroll
  for (int r = 0; r < 4; r++) { m_i[r] = -1e30f; l_i[r] = 0.f; }

  for (int s0 = 0; s0 < Tn; s0 += 64) {
    const int Dbase = s0 - t0 + 1504;
    __syncthreads();
#pragma unroll
    for (int e = 0; e < 8; e++) {
      int idx = tid + e * 128;
      int s = idx >> 4, kq = idx & 15;
      *(uint2*)(Klds + s * 72 + kq * 4) =
          *(const uint2*)(kb + (size_t)(bT + s0 + s) * 512 + h * 64 + kq * 4);
    }
#pragma unroll
    for (int e = 0; e < 12; e++) {
      int idx = tid + e * 128;
      int j = idx >> 4, kq = idx & 15;
      int jr = Dbase + j; jr = jr > 3070 ? 3070 : jr;
      *(uint2*)(RKl + j * 72 + kq * 4) =
          *(const uint2*)(rkb + (size_t)jr * 512 + h * 64 + kq * 4);
    }
    __syncthreads();

    f32x4 Sacc[4], Pacc[6];
#pragma unroll
    for (int ct = 0; ct < 4; ct++) {
      Sacc[ct] = (f32x4){0.f, 0.f, 0.f, 0.f};
#pragma unroll
      for (int ks = 0; ks < 2; ks++) {
        short8 bfr = *(const short8*)(Klds + (16 * ct + ln) * 72 + quad * 8 + ks * 32);
        Sacc[ct] = __builtin_amdgcn_mfma_f32_16x16x32_bf16(qw8[ks], bfr, Sacc[ct], 0, 0, 0);
      }
    }
#pragma unroll
    for (int jt = 0; jt < 6; jt++) {
      Pacc[jt] = (f32x4){0.f, 0.f, 0.f, 0.f};
#pragma unroll
      for (int ks = 0; ks < 2; ks++) {
        short8 bfr = *(const short8*)(RKl + (16 * jt + ln) * 72 + quad * 8 + ks * 32);
        Pacc[jt] = __builtin_amdgcn_mfma_f32_16x16x32_bf16(qr8[ks], bfr, Pacc[jt], 0, 0, 0);
      }
    }
#pragma unroll
    for (int jt = 0; jt < 6; jt++)
#pragma unroll
      for (int r = 0; r < 4; r++)
        prl[(16 * w + 4 * quad + r) * 100 + 16 * jt + ln] = Pacc[jt][r];
    __asm__ volatile("s_waitcnt lgkmcnt(0)" ::: "memory");

    float pS[4][4];
#pragma unroll
    for (int ct = 0; ct < 4; ct++)
#pragma unroll
      for (int r = 0; r < 4; r++) {
        int row = 4 * quad + r;
        int j = 16 * ct + ln - 16 * w - row + 31;
        pS[ct][r] = Sacc[ct][r] + prl[(16 * w + row) * 100 + j];
      }
    float alpha[4];
#pragma unroll
    for (int r = 0; r < 4; r++) {
      float mx = fmaxf(fmaxf(pS[0][r], pS[1][r]), fmaxf(pS[2][r], pS[3][r]));
#pragma unroll
      for (int off = 8; off >= 1; off >>= 1) mx = fmaxf(mx, __shfl_xor(mx, off));
      float mnew = fmaxf(m_i[r], mx);
      alpha[r] = __expf(m_i[r] - mnew);
      m_i[r] = mnew;
      float rs = 0.f;
#pragma unroll
      for (int ct = 0; ct < 4; ct++) {
        pS[ct][r] = __expf(pS[ct][r] - mnew);
        rs += pS[ct][r];
      }
#pragma unroll
      for (int off = 8; off >= 1; off >>= 1) rs += __shfl_xor(rs, off);
      l_i[r] = l_i[r] * alpha[r] + rs;
    }
#pragma unroll
    for (int vt = 0; vt < 12; vt++)
#pragma unroll
      for (int r = 0; r < 4; r++) Oacc[vt][r] *= alpha[r];
#pragma unroll
    for (int ct = 0; ct < 4; ct++)
#pragma unroll
      for (int r = 0; r < 4; r++)
        Pp[(16 * w + 4 * quad + r) * 72 + 16 * ct + ln] = f2bs(pS[ct][r]);
    __asm__ volatile("s_waitcnt lgkmcnt(0)" ::: "memory");

    __syncthreads();
#pragma unroll
    for (int e = 0; e < 24; e++) {
      int idx = tid + e * 128;
      int v = idx >> 4, sq = idx & 15;
      *(uint2*)(Vt + v * 72 + sq * 4) =
          *(const uint2*)(vtb + (size_t)(h * 192 + v) * 3072 + bT + s0 + sq * 4);
    }
    __syncthreads();

    short8 afr[2];
#pragma unroll
    for (int ks = 0; ks < 2; ks++)
      afr[ks] = *(const short8*)(Pp + (16 * w + ln) * 72 + quad * 8 + ks * 32);
#pragma unroll
    for (int vt = 0; vt < 12; vt++) {
#pragma unroll
      for (int ks = 0; ks < 2; ks++) {
        short8 bfr = *(const short8*)(Vt + (16 * vt + ln) * 72 + quad * 8 + ks * 32);
        Oacc[vt] = __builtin_amdgcn_mfma_f32_16x16x32_bf16(afr[ks], bfr, Oacc[vt], 0, 0, 0);
      }
    }
  }

  float inv[4];
#pragma unroll
  for (int r = 0; r < 4; r++) inv[r] = 1.f / l_i[r];
#pragma unroll
  for (int vt = 0; vt < 12; vt++)
#pragma unroll
    for (int r = 0; r < 4; r++) {
      int t = t0 + 16 * w + 4 * quad + r;
      att[(size_t)(bT + t) * 1536 + h * 192 + 16 * vt + ln] = f2bs(Oacc[vt][r] * inv[r]);
    }
}

// ---------------------------------------------------------------------------
extern "C" void kernel_launch(void* const* d_in, const int* in_sizes, int n_in,
                              void* d_out, int out_size, void* d_ws, size_t ws_size,
                              hipStream_t stream) {
  const float* x   = (const float*)d_in[0];
  const float* Wq  = (const float*)d_in[1];
  const float* Wk  = (const float*)d_in[2];
  const float* Wv  = (const float*)d_in[3];
  const float* Wr  = (const float*)d_in[4];
  const float* rwb = (const float*)d_in[5];
  const float* rrb = (const float*)d_in[6];
  const float* Wo  = (const float*)d_in[7];
  const float* bo  = (const float*)d_in[8];
  float* out = (float*)d_out;

  char* ws = (char*)d_ws;
  // xb aliases att: xb consumed by gemm_qkv (disp 7) before attn writes att.
  ushort* xb  = (ushort*)ws;                      // [3072][1536] bf16
  ushort* att = (ushort*)ws;                      // [3072][1536] bf16
  ushort* Wt  = (ushort*)(ws + 9437184);          // [2560][1536] bf16 (QKV^T)
  ushort* Wot = (ushort*)(ws + 17301504);         // [1536][1536] bf16 (Wo^T)
  ushort* qb  = (ushort*)(ws + 22020096);         // [3072][512] bf16 (scaled)
  ushort* kb  = (ushort*)(ws + 25165824);         // [3072][512] bf16
  ushort* vtb = (ushort*)(ws + 28311552);         // [1536][3072] bf16 (V^T)
  ushort* rkb = (ushort*)(ws + 37748736);         // [3071][512] bf16

  cvt_bf16<<<dim3(4608), dim3(256), 0, stream>>>(x, xb, 3072 * 1536 / 4);
  transp_bf16<<<dim3(16, 48), dim3(256), 0, stream>>>(Wq, Wt,               1536, 512);
  transp_bf16<<<dim3(16, 48), dim3(256), 0, stream>>>(Wk, Wt + 512 * 1536,  1536, 512);
  transp_bf16<<<dim3(48, 48), dim3(256), 0, stream>>>(Wv, Wt + 1024 * 1536, 1536, 1536);
  transp_bf16<<<dim3(48, 48), dim3(256), 0, stream>>>(Wo, Wot,              1536, 1536);
  rk_kernel<<<dim3(2 * Tn - 1), dim3(512), 0, stream>>>(Wr, rkb);
  gemm_qkv<<<dim3(20, 24), dim3(256), 0, stream>>>(xb, Wt, qb, kb, vtb);
  attn_mfma<<<dim3(Tn / 32, Hn, Bsz), dim3(128), 0, stream>>>(
      qb, kb, vtb, rkb, rwb, rrb, att);
  gemm_out<<<dim3(12, 24), dim3(256), 0, stream>>>(att, Wot, bo, out);
}

// Round 5
// 256.686 us; speedup vs baseline: 22.9561x; 1.3697x over previous
//
#include <hip/hip_runtime.h>
#include <hip/hip_bf16.h>

typedef __hip_bfloat16 bf16;
typedef unsigned short ushort;
typedef unsigned int uint;
typedef __attribute__((ext_vector_type(8))) short short8;
typedef __attribute__((ext_vector_type(4))) float f32x4;

#define Bsz 2
#define Tn  1536
#define Cn  1536
#define Hn  8
#define Kn  64
#define Vn  192
// H*K = 512, H*V = 1536, 2T-1 = 3071

__device__ __forceinline__ ushort f2bs(float f) {
  union { bf16 h; ushort u; } cv;
  cv.h = __float2bfloat16(f);
  return cv.u;
}
__device__ __forceinline__ float bs2f(ushort u) {
  union { float f; uint v; } cv; cv.v = ((uint)u) << 16; return cv.f;
}

// async global->LDS, 16B per lane; LDS dest = wave-uniform base + lane*16
__device__ __forceinline__ void gld_lds16(const ushort* g, ushort* l) {
  __builtin_amdgcn_global_load_lds(
      (const __attribute__((address_space(1))) uint*)g,
      (__attribute__((address_space(3))) uint*)l, 16, 0, 0);
}

// ---------------------------------------------------------------------------
// f32 -> bf16 elementwise (x), vectorized x4
// ---------------------------------------------------------------------------
__global__ __launch_bounds__(256) void cvt_bf16(const float* __restrict__ in,
                                                ushort* __restrict__ out, int n4) {
  int i = blockIdx.x * 256 + threadIdx.x;
  if (i < n4) {
    float4 v = ((const float4*)in)[i];
    uint2 o;
    o.x = (uint)f2bs(v.x) | ((uint)f2bs(v.y) << 16);
    o.y = (uint)f2bs(v.z) | ((uint)f2bs(v.w) << 16);
    ((uint2*)out)[i] = o;
  }
}

// ---------------------------------------------------------------------------
// transpose + convert: in f32 [R][Cc] -> out bf16 [Cc][R]. 32x32 LDS tiles.
// ---------------------------------------------------------------------------
__global__ __launch_bounds__(256) void transp_bf16(const float* __restrict__ in,
                                                   ushort* __restrict__ out,
                                                   int R, int Cc) {
  __shared__ float tile[32][33];
  const int bx = blockIdx.x * 32;
  const int by = blockIdx.y * 32;
  const int tx = threadIdx.x & 31, ty = threadIdx.x >> 5;
#pragma unroll
  for (int i = 0; i < 32; i += 8)
    tile[ty + i][tx] = in[(size_t)(by + ty + i) * Cc + bx + tx];
  __syncthreads();
#pragma unroll
  for (int i = 0; i < 32; i += 8)
    out[(size_t)(bx + ty + i) * R + by + tx] = f2bs(tile[tx][ty + i]);
}

// ---------------------------------------------------------------------------
// rk[r,c] (bf16) from the Borzoi central-mask basis (double widths; margins
// to integers >= 0.02 so no comparison flips vs the fp32 reference).
// ---------------------------------------------------------------------------
__global__ __launch_bounds__(512) void rk_kernel(const float* __restrict__ Wr,
                                                 ushort* __restrict__ rk) {
  const int r = blockIdx.x;
  const int c = threadIdx.x;
  const float d = (float)(r - (Tn - 1));
  const float ad = fabsf(d);
  const float sg = (d > 0.f) ? 1.f : ((d < 0.f) ? -1.f : 0.f);
  float acc = 0.f;
#pragma unroll
  for (int i = 0; i < 16; i++) {
    double cw = exp(log((double)(Tn + 1)) * (double)(i + 1) / 16.0) - 1.0;
    if ((float)cw > ad) acc += Wr[i * 512 + c] + sg * Wr[(16 + i) * 512 + c];
  }
  rk[(size_t)r * 512 + c] = f2bs(acc);
}

// ---------------------------------------------------------------------------
// Fused QKV MFMA GEMM (unchanged from r4): xb @ Wt^T-layout -> qb/kb/vtb.
// ---------------------------------------------------------------------------
__global__ __launch_bounds__(256) void gemm_qkv(
    const ushort* __restrict__ xb, const ushort* __restrict__ Wt,
    ushort* __restrict__ qb, ushort* __restrict__ kb, ushort* __restrict__ vtb) {
  __shared__ ushort Al[128 * 32];
  __shared__ ushort Bl[128 * 32];
  const int tid = threadIdx.x;
  const int w = tid >> 6, lane = tid & 63, quad = lane >> 4, ln = lane & 15;
  const int bm = blockIdx.y * 128, bn = blockIdx.x * 128;
  const int wm = (w & 1) * 64, wn = (w >> 1) * 64;
  f32x4 acc[4][4];
#pragma unroll
  for (int i = 0; i < 4; i++)
#pragma unroll
    for (int j = 0; j < 4; j++) acc[i][j] = (f32x4){0.f, 0.f, 0.f, 0.f};

  for (int k0 = 0; k0 < 1536; k0 += 32) {
    __syncthreads();
#pragma unroll
    for (int st = 0; st < 2; st++) {
      int idx = tid + st * 256;
      int row = idx >> 2, col = (idx & 3) * 8;
      gld_lds16(xb + (size_t)(bm + row) * 1536 + k0 + col, Al + idx * 8);
      gld_lds16(Wt + (size_t)(bn + row) * 1536 + k0 + col, Bl + idx * 8);
    }
    __syncthreads();
    short8 af[4], bfr[4];
#pragma unroll
    for (int t = 0; t < 4; t++) {
      af[t]  = *(const short8*)(Al + (wm + t * 16 + ln) * 32 + quad * 8);
      bfr[t] = *(const short8*)(Bl + (wn + t * 16 + ln) * 32 + quad * 8);
    }
#pragma unroll
    for (int mt = 0; mt < 4; mt++)
#pragma unroll
      for (int nt = 0; nt < 4; nt++)
        acc[mt][nt] = __builtin_amdgcn_mfma_f32_16x16x32_bf16(
            af[mt], bfr[nt], acc[mt][nt], 0, 0, 0);
  }

  if (bn < 512) {
#pragma unroll
    for (int mt = 0; mt < 4; mt++)
#pragma unroll
      for (int nt = 0; nt < 4; nt++)
#pragma unroll
        for (int r = 0; r < 4; r++) {
          int m = bm + wm + mt * 16 + quad * 4 + r;
          int n = bn + wn + nt * 16 + ln;
          qb[(size_t)m * 512 + n] = f2bs(acc[mt][nt][r] * 0.125f);
        }
  } else if (bn < 1024) {
#pragma unroll
    for (int mt = 0; mt < 4; mt++)
#pragma unroll
      for (int nt = 0; nt < 4; nt++)
#pragma unroll
        for (int r = 0; r < 4; r++) {
          int m = bm + wm + mt * 16 + quad * 4 + r;
          int n = bn - 512 + wn + nt * 16 + ln;
          kb[(size_t)m * 512 + n] = f2bs(acc[mt][nt][r]);
        }
  } else {
#pragma unroll
    for (int mt = 0; mt < 4; mt++)
#pragma unroll
      for (int nt = 0; nt < 4; nt++) {
        int vcol = bn - 1024 + wn + nt * 16 + ln;
        int m0 = bm + wm + mt * 16 + quad * 4;
        uint2 val;
        val.x = (uint)f2bs(acc[mt][nt][0]) | ((uint)f2bs(acc[mt][nt][1]) << 16);
        val.y = (uint)f2bs(acc[mt][nt][2]) | ((uint)f2bs(acc[mt][nt][3]) << 16);
        *(uint2*)(vtb + (size_t)vcol * 3072 + m0) = val;
      }
  }
}

// ---------------------------------------------------------------------------
// Output MFMA GEMM (unchanged from r4): att(bf16) @ Wot + bo -> f32 out.
// ---------------------------------------------------------------------------
__global__ __launch_bounds__(256) void gemm_out(
    const ushort* __restrict__ att, const ushort* __restrict__ Wot,
    const float* __restrict__ bo, float* __restrict__ out) {
  __shared__ ushort Al[128 * 32];
  __shared__ ushort Bl[128 * 32];
  const int tid = threadIdx.x;
  const int w = tid >> 6, lane = tid & 63, quad = lane >> 4, ln = lane & 15;
  const int bm = blockIdx.y * 128, bn = blockIdx.x * 128;
  const int wm = (w & 1) * 64, wn = (w >> 1) * 64;
  f32x4 acc[4][4];
#pragma unroll
  for (int i = 0; i < 4; i++)
#pragma unroll
    for (int j = 0; j < 4; j++) acc[i][j] = (f32x4){0.f, 0.f, 0.f, 0.f};

  for (int k0 = 0; k0 < 1536; k0 += 32) {
    __syncthreads();
#pragma unroll
    for (int st = 0; st < 2; st++) {
      int idx = tid + st * 256;
      int row = idx >> 2, col = (idx & 3) * 8;
      gld_lds16(att + (size_t)(bm + row) * 1536 + k0 + col, Al + idx * 8);
      gld_lds16(Wot + (size_t)(bn + row) * 1536 + k0 + col, Bl + idx * 8);
    }
    __syncthreads();
    short8 af[4], bfr[4];
#pragma unroll
    for (int t = 0; t < 4; t++) {
      af[t]  = *(const short8*)(Al + (wm + t * 16 + ln) * 32 + quad * 8);
      bfr[t] = *(const short8*)(Bl + (wn + t * 16 + ln) * 32 + quad * 8);
    }
#pragma unroll
    for (int mt = 0; mt < 4; mt++)
#pragma unroll
      for (int nt = 0; nt < 4; nt++)
        acc[mt][nt] = __builtin_amdgcn_mfma_f32_16x16x32_bf16(
            af[mt], bfr[nt], acc[mt][nt], 0, 0, 0);
  }
#pragma unroll
  for (int mt = 0; mt < 4; mt++)
#pragma unroll
    for (int nt = 0; nt < 4; nt++)
#pragma unroll
      for (int r = 0; r < 4; r++) {
        int m = bm + wm + mt * 16 + quad * 4 + r;
        int n = bn + wn + nt * 16 + ln;
        out[(size_t)m * 1536 + n] = acc[mt][nt][r] + bo[n];
      }
}

// ---------------------------------------------------------------------------
// MFMA flash attention, split-K(x2), t-tile 64, 4 waves, DMA staging.
// Block = (t-tile 24, h 8, b*2+sk 4). Each wave owns 16 q-rows.
// LDS [46080B]: K[64]x128B @0, RK[128]x128B @8192 (V[192]x128B overlays both);
//   per-wave 5376B scratch @24576: prl f32[16][84] overlaid by Pp bf16[16][72].
// XOR swizzle: 16B chunk c of row r stored at physical chunk c^(r&7).
// Rel: j = (s-s0)-(t-t0)+63 in [0,127); wave w needs j-tiles 3-w..7-w (5).
// Partials: normalized O (bf16) + (m,l) per row; combined by attn_combine.
// ---------------------------------------------------------------------------
__global__ __launch_bounds__(256, 3) void attn_mfma(
    const ushort* __restrict__ qb, const ushort* __restrict__ kb,
    const ushort* __restrict__ vtb, const ushort* __restrict__ rkb,
    const float* __restrict__ rwb, const float* __restrict__ rrb,
    ushort* __restrict__ op0, ushort* __restrict__ op1,
    float2* __restrict__ mlb) {
  __shared__ __align__(16) char smem[46080];
  ushort* Kl  = (ushort*)smem;              // [64] rows x 128B
  ushort* RKl = (ushort*)(smem + 8192);     // [128] rows x 128B
  ushort* Vl  = (ushort*)smem;              // [192] rows x 128B (overlay)

  const int t0 = blockIdx.x * 64;
  const int h  = blockIdx.y;
  const int b  = blockIdx.z >> 1;
  const int sk = blockIdx.z & 1;
  const int bT = b * Tn;
  const int tid = threadIdx.x;
  const int w = tid >> 6, lane = tid & 63, quad = lane >> 4, ln = lane & 15;

  float*  prl = (float*)(smem + 24576 + w * 5376);   // [16][84] f32
  ushort* Pp  = (ushort*)(smem + 24576 + w * 5376);  // [16][72] bf16 (overlay)

  const int lr  = lane >> 3;          // staging: row-in-chunk 0..7
  const int lcx = (lane & 7) ^ lr;    // staging: logical 16B chunk (swizzle)

  // Q fragments (A-layout m=ln, k=quad*8+ks*32+e), + biases
  short8 qw8[2], qr8[2];
  {
    const ushort* qrow = qb + (size_t)(bT + t0 + 16 * w + ln) * 512 + h * 64;
#pragma unroll
    for (int ks = 0; ks < 2; ks++) {
      int k0 = quad * 8 + ks * 32;
#pragma unroll
      for (int e = 0; e < 8; e++) {
        float qv = bs2f(qrow[k0 + e]);
        qw8[ks][e] = (short)f2bs(qv + rwb[h * 64 + k0 + e]);
        qr8[ks][e] = (short)f2bs(qv + rrb[h * 64 + k0 + e]);
      }
    }
  }

  f32x4 Oacc[12];
  float m_i[4], l_i[4];
#pragma unroll
  for (int vt = 0; vt < 12; vt++) Oacc[vt] = (f32x4){0.f, 0.f, 0.f, 0.f};
#pragma unroll
  for (int r = 0; r < 4; r++) { m_i[r] = -1e30f; l_i[r] = 0.f; }

  for (int ch = 0; ch < 12; ch++) {
    const int s0 = sk * 768 + ch * 64;
    const int Dbase = s0 - t0 + 1472;
    __syncthreads();   // prev PV done reading Vl (overlay with K/RK)
    // stage K (8 KB, 8 chunks of 1KB; 2 per wave)
#pragma unroll
    for (int i = 0; i < 2; i++) {
      int kc = w * 2 + i, sr = kc * 8 + lr;
      gld_lds16(kb + (size_t)(bT + s0 + sr) * 512 + h * 64 + lcx * 8,
                (ushort*)(smem + kc * 1024) + lane * 8);
    }
    // stage RK (16 KB, 16 chunks; 4 per wave). j=127 unused -> clamp.
#pragma unroll
    for (int i = 0; i < 4; i++) {
      int kc = w * 4 + i, j = kc * 8 + lr;
      int jr = Dbase + j; jr = jr > 3070 ? 3070 : jr;
      gld_lds16(rkb + (size_t)jr * 512 + h * 64 + lcx * 8,
                (ushort*)(smem + 8192 + kc * 1024) + lane * 8);
    }
    __syncthreads();

    // ---- S phase ----
    f32x4 Sacc[4], Pacc[5];
#pragma unroll
    for (int ct = 0; ct < 4; ct++) {
      Sacc[ct] = (f32x4){0.f, 0.f, 0.f, 0.f};
#pragma unroll
      for (int ks = 0; ks < 2; ks++) {
        short8 bfr = *(const short8*)(
            Kl + (16 * ct + ln) * 64 + ((quad + 4 * ks) ^ (ln & 7)) * 8);
        Sacc[ct] = __builtin_amdgcn_mfma_f32_16x16x32_bf16(qw8[ks], bfr, Sacc[ct], 0, 0, 0);
      }
    }
#pragma unroll
    for (int jtl = 0; jtl < 5; jtl++) {
      int jt = 3 - w + jtl;
      Pacc[jtl] = (f32x4){0.f, 0.f, 0.f, 0.f};
#pragma unroll
      for (int ks = 0; ks < 2; ks++) {
        short8 bfr = *(const short8*)(
            RKl + (16 * jt + ln) * 64 + ((quad + 4 * ks) ^ (ln & 7)) * 8);
        Pacc[jtl] = __builtin_amdgcn_mfma_f32_16x16x32_bf16(qr8[ks], bfr, Pacc[jtl], 0, 0, 0);
      }
    }
    // rel logits (C-layout) -> per-wave prl; local col jl = 16*jtl + ln
#pragma unroll
    for (int jtl = 0; jtl < 5; jtl++)
#pragma unroll
      for (int r = 0; r < 4; r++)
        prl[(4 * quad + r) * 84 + 16 * jtl + ln] = Pacc[jtl][r];
    __asm__ volatile("s_waitcnt lgkmcnt(0)" ::: "memory");

    // gather: jl = 16ct + ln - row + 15 (row = wave-local q-row)
    float pS[4][4];
#pragma unroll
    for (int ct = 0; ct < 4; ct++)
#pragma unroll
      for (int r = 0; r < 4; r++) {
        int row = 4 * quad + r;
        pS[ct][r] = Sacc[ct][r] + prl[row * 84 + 16 * ct + ln - row + 15];
      }
    // online softmax (row lives in the 16 lanes of this quad)
    float alpha[4];
#pragma unroll
    for (int r = 0; r < 4; r++) {
      float mx = fmaxf(fmaxf(pS[0][r], pS[1][r]), fmaxf(pS[2][r], pS[3][r]));
#pragma unroll
      for (int off = 8; off >= 1; off >>= 1) mx = fmaxf(mx, __shfl_xor(mx, off));
      float mnew = fmaxf(m_i[r], mx);
      alpha[r] = __expf(m_i[r] - mnew);
      m_i[r] = mnew;
      float rs = 0.f;
#pragma unroll
      for (int ct = 0; ct < 4; ct++) {
        pS[ct][r] = __expf(pS[ct][r] - mnew);
        rs += pS[ct][r];
      }
#pragma unroll
      for (int off = 8; off >= 1; off >>= 1) rs += __shfl_xor(rs, off);
      l_i[r] = l_i[r] * alpha[r] + rs;
    }
#pragma unroll
    for (int vt = 0; vt < 12; vt++)
#pragma unroll
      for (int r = 0; r < 4; r++) Oacc[vt][r] *= alpha[r];
    // probs -> Pp (bf16, overlays prl; all prl reads precede, same wave = safe)
#pragma unroll
    for (int ct = 0; ct < 4; ct++)
#pragma unroll
      for (int r = 0; r < 4; r++)
        Pp[(4 * quad + r) * 72 + 16 * ct + ln] = f2bs(pS[ct][r]);

    __syncthreads();   // all waves done with K/RK
    // stage V (24 KB, 24 chunks; 6 per wave) over K+RK region
#pragma unroll
    for (int i = 0; i < 6; i++) {
      int kc = w * 6 + i, vr = kc * 8 + lr;
      gld_lds16(vtb + (size_t)(h * 192 + vr) * 3072 + bT + s0 + lcx * 8,
                (ushort*)(smem + kc * 1024) + lane * 8);
    }
    __syncthreads();

    // ---- PV phase ----
    short8 afr[2];
#pragma unroll
    for (int ks = 0; ks < 2; ks++)
      afr[ks] = *(const short8*)(Pp + ln * 72 + quad * 8 + ks * 32);
#pragma unroll
    for (int vt = 0; vt < 12; vt++) {
#pragma unroll
      for (int ks = 0; ks < 2; ks++) {
        short8 bfr = *(const short8*)(
            Vl + (16 * vt + ln) * 64 + ((quad + 4 * ks) ^ (ln & 7)) * 8);
        Oacc[vt] = __builtin_amdgcn_mfma_f32_16x16x32_bf16(afr[ks], bfr, Oacc[vt], 0, 0, 0);
      }
    }
  }

  // epilogue: normalized bf16 partial + (m,l)
  ushort* op = sk ? op1 : op0;
  float inv[4];
#pragma unroll
  for (int r = 0; r < 4; r++) inv[r] = 1.f / l_i[r];
#pragma unroll
  for (int vt = 0; vt < 12; vt++)
#pragma unroll
    for (int r = 0; r < 4; r++) {
      int t = t0 + 16 * w + 4 * quad + r;
      op[(size_t)(bT + t) * 1536 + h * 192 + 16 * vt + ln] = f2bs(Oacc[vt][r] * inv[r]);
    }
  if (ln == 0) {
#pragma unroll
    for (int r = 0; r < 4; r++) {
      int t = t0 + 16 * w + 4 * quad + r;
      float2 v; v.x = m_i[r]; v.y = l_i[r];
      mlb[((sk * 2 + b) * 8 + h) * 1536 + t] = v;
    }
  }
}

// ---------------------------------------------------------------------------
// Combine the two split-K partials: O = sum_i e^{m_i-M} l_i O_i / sum e^{m-M} l
// ---------------------------------------------------------------------------
__global__ __launch_bounds__(256) void attn_combine(
    const ushort* __restrict__ op0, const ushort* __restrict__ op1,
    const float2* __restrict__ mlb, ushort* __restrict__ att) {
  int g = blockIdx.x * 256 + threadIdx.x;   // group of 4 bf16
  int row = g / 384;                        // 0..3071
  int c4 = (g - row * 384) * 4;             // 0..1532
  int b = row >> 11 ? 1 : (row >= 1536);    // row/1536 (row<3072)
  int t = row - b * 1536;
  int h = c4 / 192;
  float2 ml0 = mlb[((0 + b) * 8 + h) * 1536 + t];
  float2 ml1 = mlb[((2 + b) * 8 + h) * 1536 + t];
  float M = fmaxf(ml0.x, ml1.x);
  float w0 = __expf(ml0.x - M) * ml0.y;
  float w1 = __expf(ml1.x - M) * ml1.y;
  float inv = 1.f / (w0 + w1);
  w0 *= inv; w1 *= inv;
  size_t off = (size_t)row * 1536 + c4;
  uint2 a = *(const uint2*)(op0 + off);
  uint2 c = *(const uint2*)(op1 + off);
  uint2 o;
  float r0 = w0 * bs2f((ushort)(a.x & 0xffff)) + w1 * bs2f((ushort)(c.x & 0xffff));
  float r1 = w0 * bs2f((ushort)(a.x >> 16))    + w1 * bs2f((ushort)(c.x >> 16));
  float r2 = w0 * bs2f((ushort)(a.y & 0xffff)) + w1 * bs2f((ushort)(c.y & 0xffff));
  float r3 = w0 * bs2f((ushort)(a.y >> 16))    + w1 * bs2f((ushort)(c.y >> 16));
  o.x = (uint)f2bs(r0) | ((uint)f2bs(r1) << 16);
  o.y = (uint)f2bs(r2) | ((uint)f2bs(r3) << 16);
  *(uint2*)(att + off) = o;
}

// ---------------------------------------------------------------------------
extern "C" void kernel_launch(void* const* d_in, const int* in_sizes, int n_in,
                              void* d_out, int out_size, void* d_ws, size_t ws_size,
                              hipStream_t stream) {
  const float* x   = (const float*)d_in[0];
  const float* Wq  = (const float*)d_in[1];
  const float* Wk  = (const float*)d_in[2];
  const float* Wv  = (const float*)d_in[3];
  const float* Wr  = (const float*)d_in[4];
  const float* rwb = (const float*)d_in[5];
  const float* rrb = (const float*)d_in[6];
  const float* Wo  = (const float*)d_in[7];
  const float* bo  = (const float*)d_in[8];
  float* out = (float*)d_out;

  char* ws = (char*)d_ws;
  // Region A [0, 9437184): xb (cvt->qkv) -> op1 (attn) -> att (combine, same
  // addresses elementwise) -> gemm_out input.
  ushort* xb  = (ushort*)ws;
  ushort* op1 = (ushort*)ws;
  ushort* att = (ushort*)ws;
  ushort* Wot = (ushort*)(ws + 9437184);    // [1536][1536] bf16, until gemm_out
  ushort* Wt  = (ushort*)(ws + 14155776);   // [2560][1536] bf16, until gemm_qkv
  ushort* op0 = (ushort*)(ws + 14155776);   // overlays dead Wt (attn phase)
  ushort* qb  = (ushort*)(ws + 23592960);   // [3072][512] bf16 (scaled)
  ushort* kb  = (ushort*)(ws + 26738688);   // [3072][512] bf16
  ushort* vtb = (ushort*)(ws + 29884416);   // [1536][3072] bf16 (V^T)
  ushort* rkb = (ushort*)(ws + 39321600);   // [3071][512] bf16
  float2* mlb = (float2*)(ws + 42467328);   // [2][2][8][1536] (m,l)

  cvt_bf16<<<dim3(4608), dim3(256), 0, stream>>>(x, xb, 3072 * 1536 / 4);
  transp_bf16<<<dim3(16, 48), dim3(256), 0, stream>>>(Wq, Wt,               1536, 512);
  transp_bf16<<<dim3(16, 48), dim3(256), 0, stream>>>(Wk, Wt + 512 * 1536,  1536, 512);
  transp_bf16<<<dim3(48, 48), dim3(256), 0, stream>>>(Wv, Wt + 1024 * 1536, 1536, 1536);
  transp_bf16<<<dim3(48, 48), dim3(256), 0, stream>>>(Wo, Wot,              1536, 1536);
  rk_kernel<<<dim3(2 * Tn - 1), dim3(512), 0, stream>>>(Wr, rkb);
  gemm_qkv<<<dim3(20, 24), dim3(256), 0, stream>>>(xb, Wt, qb, kb, vtb);
  attn_mfma<<<dim3(24, 8, 4), dim3(256), 0, stream>>>(
      qb, kb, vtb, rkb, rwb, rrb, op0, op1, mlb);
  attn_combine<<<dim3(4608), dim3(256), 0, stream>>>(op0, op1, mlb, att);
  gemm_out<<<dim3(12, 24), dim3(256), 0, stream>>>(att, Wot, bo, out);
}